// Round 1
// baseline (7579.671 us; speedup 1.0000x reference)
//
#include <hip/hip_runtime.h>
#include <math.h>

#define NN 100000
#define NE 800000
#define DD 128

// ---------------------------------------------------------------- row means
__global__ void rowmean_kernel(const float* __restrict__ tab, float* __restrict__ rm) {
    int r = blockIdx.x;           // 7 blocks
    int t = threadIdx.x;          // 128 threads
    float v = tab[r * DD + t];
    #pragma unroll
    for (int o = 32; o > 0; o >>= 1) v += __shfl_xor(v, o);
    __shared__ float red[2];
    if ((t & 63) == 0) red[t >> 6] = v;
    __syncthreads();
    if (t == 0) rm[r] = (red[0] + red[1]) * (1.0f / DD);
}

// ---------------------------------------------------------------- edge weights
__global__ void ew_kernel(const int* __restrict__ et, const float* __restrict__ rm,
                          float* __restrict__ ew) {
    int e = blockIdx.x * 256 + threadIdx.x;
    if (e < NE) ew[e] = rm[et[e] - 1];
}

// ---------------------------------------------------------------- embedding gather
__global__ void embed_kernel(const int* __restrict__ ids, const float* __restrict__ tab,
                             float* __restrict__ x) {
    int tid = blockIdx.x * 256 + threadIdx.x;   // NN*32 threads
    int n = tid >> 5, c = tid & 31;
    if (n < NN) {
        const float4* srcp = (const float4*)(tab + (size_t)(ids[n] + 1) * DD);
        ((float4*)(x + (size_t)n * DD))[c] = srcp[c];
    }
}

// ---------------------------------------------------------------- m = x @ W  (W is [k][d] row-major)
__global__ __launch_bounds__(512) void gemm_m_kernel(const float* __restrict__ x,
                                                     const float* __restrict__ W,
                                                     float* __restrict__ out) {
    __shared__ float sX[64 * DD];   // 32 KB
    __shared__ float sW[DD * DD];   // 64 KB, layout [k][d] (same as global)
    int t = threadIdx.x;
    int b0 = blockIdx.x * 64;
    #pragma unroll
    for (int it = 0; it < 4; ++it) {
        int idx = it * 512 + t;          // float4 slots, 2048 total
        int n = idx >> 5, c = idx & 31;
        int row = b0 + n;
        float4 v = make_float4(0.f, 0.f, 0.f, 0.f);
        if (row < NN) v = ((const float4*)(x + (size_t)row * DD))[c];
        ((float4*)sX)[idx] = v;
    }
    #pragma unroll
    for (int it = 0; it < 8; ++it) {
        int idx = it * 512 + t;          // 4096 float4 slots
        ((float4*)sW)[idx] = ((const float4*)W)[idx];
    }
    __syncthreads();
    int ng = t >> 5, dg = t & 31;
    float acc[4][4];
    #pragma unroll
    for (int i = 0; i < 4; ++i)
        #pragma unroll
        for (int j = 0; j < 4; ++j) acc[i][j] = 0.f;
    #pragma unroll 4
    for (int k = 0; k < DD; ++k) {
        float4 w4 = ((const float4*)(sW + k * DD))[dg];
        #pragma unroll
        for (int i = 0; i < 4; ++i) {
            float a = sX[(ng + 16 * i) * DD + k];
            acc[i][0] += a * w4.x; acc[i][1] += a * w4.y;
            acc[i][2] += a * w4.z; acc[i][3] += a * w4.w;
        }
    }
    #pragma unroll
    for (int i = 0; i < 4; ++i) {
        int row = b0 + ng + 16 * i;
        if (row < NN) {
            float4 v = make_float4(acc[i][0], acc[i][1], acc[i][2], acc[i][3]);
            ((float4*)(out + (size_t)row * DD))[dg] = v;
        }
    }
}

// ---------------------------------------------------------------- scatter-add (atomics)
__global__ void scatter_kernel(const float* __restrict__ m, const float* __restrict__ ew,
                               const int* __restrict__ src, const int* __restrict__ dst,
                               float* __restrict__ agg) {
    int tid = blockIdx.x * 256 + threadIdx.x;   // NE*32 threads
    int e = tid >> 5, c = tid & 31;
    float w = ew[e];
    int s = src[e], d = dst[e];
    float4 v = ((const float4*)(m + (size_t)s * DD))[c];
    float* ap = agg + (size_t)d * DD + 4 * c;
    atomicAdd(ap + 0, v.x * w);
    atomicAdd(ap + 1, v.y * w);
    atomicAdd(ap + 2, v.z * w);
    atomicAdd(ap + 3, v.w * w);
}

// ---------------------------------------------------------------- fused GRU
__device__ __forceinline__ void tile_mm(float acc[4][4], const float* __restrict__ sIn,
                                        const float* __restrict__ sW, int ng, int dg) {
    #pragma unroll 4
    for (int k = 0; k < DD; ++k) {
        float4 w4 = ((const float4*)(sW + k * DD))[dg];
        #pragma unroll
        for (int i = 0; i < 4; ++i) {
            float a = sIn[(ng + 16 * i) * DD + k];
            acc[i][0] += a * w4.x; acc[i][1] += a * w4.y;
            acc[i][2] += a * w4.z; acc[i][3] += a * w4.w;
        }
    }
}

__device__ __forceinline__ void stage_wT(float* __restrict__ sW, const float* __restrict__ Wg,
                                         int t) {
    // sW[k*DD + d] = Wg[d*DD + k]  (transpose into LDS; conflict-free reads in tile_mm)
    #pragma unroll
    for (int it = 0; it < 8; ++it) {
        int idx = it * 512 + t;          // 4096 float4 loads
        int d = idx & 127, kc = idx >> 7;
        float4 gv = ((const float4*)(Wg + d * DD))[kc];
        sW[(4 * kc + 0) * DD + d] = gv.x;
        sW[(4 * kc + 1) * DD + d] = gv.y;
        sW[(4 * kc + 2) * DD + d] = gv.z;
        sW[(4 * kc + 3) * DD + d] = gv.w;
    }
}

__global__ __launch_bounds__(512) void gru_kernel(const float* __restrict__ agg,
                                                  const float* __restrict__ x,
                                                  const float* __restrict__ Wih,
                                                  const float* __restrict__ Whh,
                                                  const float* __restrict__ bih,
                                                  const float* __restrict__ bhh,
                                                  float* __restrict__ xout) {
    __shared__ float sA[64 * DD];   // 32 KB
    __shared__ float sX[64 * DD];   // 32 KB
    __shared__ float sW[DD * DD];   // 64 KB
    int t = threadIdx.x;
    int b0 = blockIdx.x * 64;
    #pragma unroll
    for (int it = 0; it < 4; ++it) {
        int idx = it * 512 + t;
        int n = idx >> 5, c = idx & 31;
        int row = b0 + n;
        float4 va = make_float4(0.f, 0.f, 0.f, 0.f);
        float4 vx = va;
        if (row < NN) {
            va = ((const float4*)(agg + (size_t)row * DD))[c];
            vx = ((const float4*)(x + (size_t)row * DD))[c];
        }
        ((float4*)sA)[idx] = va;
        ((float4*)sX)[idx] = vx;
    }
    int ng = t >> 5, dg = t & 31;
    float rv[4][4], zv[4][4], xn[4][4];
    for (int g = 0; g < 3; ++g) {
        __syncthreads();                       // protect sW from prior phase
        stage_wT(sW, Wih + g * DD * DD, t);
        __syncthreads();
        float gi[4][4];
        #pragma unroll
        for (int i = 0; i < 4; ++i)
            #pragma unroll
            for (int j = 0; j < 4; ++j) gi[i][j] = 0.f;
        tile_mm(gi, sA, sW, ng, dg);
        float4 bi4 = ((const float4*)(bih + g * DD))[dg];
        __syncthreads();
        stage_wT(sW, Whh + g * DD * DD, t);
        __syncthreads();
        float gh[4][4];
        #pragma unroll
        for (int i = 0; i < 4; ++i)
            #pragma unroll
            for (int j = 0; j < 4; ++j) gh[i][j] = 0.f;
        tile_mm(gh, sX, sW, ng, dg);
        float4 bh4 = ((const float4*)(bhh + g * DD))[dg];
        float bi[4] = {bi4.x, bi4.y, bi4.z, bi4.w};
        float bh[4] = {bh4.x, bh4.y, bh4.z, bh4.w};
        #pragma unroll
        for (int i = 0; i < 4; ++i) {
            #pragma unroll
            for (int j = 0; j < 4; ++j) {
                float giv = gi[i][j] + bi[j];
                float ghv = gh[i][j] + bh[j];
                if (g == 0) {
                    rv[i][j] = 1.0f / (1.0f + expf(-(giv + ghv)));
                } else if (g == 1) {
                    zv[i][j] = 1.0f / (1.0f + expf(-(giv + ghv)));
                } else {
                    float nv = tanhf(giv + rv[i][j] * ghv);
                    float xo = sX[(ng + 16 * i) * DD + 4 * dg + j];
                    xn[i][j] = (1.0f - zv[i][j]) * nv + zv[i][j] * xo;
                }
            }
        }
    }
    #pragma unroll
    for (int i = 0; i < 4; ++i) {
        int row = b0 + ng + 16 * i;
        if (row < NN) {
            float4 v = make_float4(xn[i][0], xn[i][1], xn[i][2], xn[i][3]);
            ((float4*)(xout + (size_t)row * DD))[dg] = v;
        }
    }
}

// ---------------------------------------------------------------- pooling
__global__ void pool1_kernel(const float* __restrict__ x, const float* __restrict__ gw,
                             const float* __restrict__ gb, float* __restrict__ p) {
    int w = threadIdx.x >> 6, lane = threadIdx.x & 63;
    int n = blockIdx.x * 4 + w;                 // NN = 4 * 25000 exactly
    float v = x[(size_t)n * DD + lane] * gw[lane] +
              x[(size_t)n * DD + 64 + lane] * gw[64 + lane];
    #pragma unroll
    for (int o = 32; o > 0; o >>= 1) v += __shfl_xor(v, o);
    if (lane == 0) {
        float s = 1.0f / (1.0f + expf(-(v + gb[0])));
        p[n] = expf(s);                          // s in (0,1): no max-subtract needed
    }
}

__global__ void pool2_kernel(const float* __restrict__ x, const float* __restrict__ p,
                             float* __restrict__ accum, float* __restrict__ den) {
    int t = threadIdx.x;
    int d = t & 127, g = t >> 7;
    int base = blockIdx.x * 256 + g * 128;
    float acc = 0.f, ps = 0.f;
    for (int j = 0; j < 128; ++j) {
        int n = base + j;
        if (n < NN) {
            float pv = p[n];
            acc += pv * x[(size_t)n * DD + d];
            ps += pv;
        }
    }
    __shared__ float red[256];
    __shared__ float rps[2];
    red[t] = acc;
    if (d == 0) rps[g] = ps;
    __syncthreads();
    if (g == 0) {
        atomicAdd(&accum[d], acc + red[128 + d]);
        if (t == 0) atomicAdd(den, rps[0] + rps[1]);
    }
}

__global__ void finalize_kernel(const float* __restrict__ accum, const float* __restrict__ den,
                                float* __restrict__ out) {
    out[threadIdx.x] = accum[threadIdx.x] / den[0];
}

// ---------------------------------------------------------------- launch
extern "C" void kernel_launch(void* const* d_in, const int* in_sizes, int n_in,
                              void* d_out, int out_size, void* d_ws, size_t ws_size,
                              hipStream_t stream) {
    const int*   node_ids    = (const int*)d_in[0];
    const int*   edges       = (const int*)d_in[1];
    const int*   edge_types  = (const int*)d_in[2];
    const float* embed_table = (const float*)d_in[3];
    const float* edge_tab    = (const float*)d_in[4];
    const float* ggnn_w      = (const float*)d_in[5];
    const float* Wih         = (const float*)d_in[6];
    const float* Whh         = (const float*)d_in[7];
    const float* bih         = (const float*)d_in[8];
    const float* bhh         = (const float*)d_in[9];
    const float* gate_w      = (const float*)d_in[10];
    const float* gate_b      = (const float*)d_in[11];
    float* out = (float*)d_out;

    float* ws    = (float*)d_ws;
    float* x     = ws;                          // N*D
    float* m     = x + (size_t)NN * DD;         // N*D (doubles as x_next)
    float* agg   = m + (size_t)NN * DD;         // N*D
    float* ew    = agg + (size_t)NN * DD;       // E
    float* p     = ew + NE;                     // N
    float* accum = p + NN;                      // 128
    float* den   = accum + DD;                  // 1
    float* rm    = den + 1;                     // 7

    const int* src = edges;
    const int* dst = edges + NE;

    rowmean_kernel<<<7, 128, 0, stream>>>(edge_tab, rm);
    ew_kernel<<<(NE + 255) / 256, 256, 0, stream>>>(edge_types, rm, ew);
    embed_kernel<<<NN * 32 / 256, 256, 0, stream>>>(node_ids, embed_table, x);

    for (int layer = 0; layer < 4; ++layer) {
        gemm_m_kernel<<<(NN + 63) / 64, 512, 0, stream>>>(x, ggnn_w + (size_t)layer * DD * DD, m);
        hipMemsetAsync(agg, 0, (size_t)NN * DD * sizeof(float), stream);
        scatter_kernel<<<NE * 32 / 256, 256, 0, stream>>>(m, ew, src, dst, agg);
        gru_kernel<<<(NN + 63) / 64, 512, 0, stream>>>(agg, x, Wih, Whh, bih, bhh, m);
        float* tmp = x; x = m; m = tmp;
    }

    hipMemsetAsync(accum, 0, (DD + 1) * sizeof(float), stream);
    pool1_kernel<<<NN / 4, 256, 0, stream>>>(x, gate_w, gate_b, p);
    pool2_kernel<<<(NN + 255) / 256, 256, 0, stream>>>(x, p, accum, den);
    finalize_kernel<<<1, 128, 0, stream>>>(accum, den, out);
}

// Round 2
// 2079.636 us; speedup vs baseline: 3.6447x; 3.6447x over previous
//
#include <hip/hip_runtime.h>
#include <math.h>

#define NN 100000
#define NE 800000
#define DD 128

// ---------------------------------------------------------------- row means of edge-type table
__global__ void rowmean_kernel(const float* __restrict__ tab, float* __restrict__ rm) {
    int r = blockIdx.x;           // 7 blocks
    int t = threadIdx.x;          // 128 threads
    float v = tab[r * DD + t];
    #pragma unroll
    for (int o = 32; o > 0; o >>= 1) v += __shfl_xor(v, o);
    __shared__ float red[2];
    if ((t & 63) == 0) red[t >> 6] = v;
    __syncthreads();
    if (t == 0) rm[r] = (red[0] + red[1]) * (1.0f / DD);
}

// ---------------------------------------------------------------- CSR build: histogram of dst
__global__ void hist_kernel(const int* __restrict__ dst, int* __restrict__ fill) {
    int e = blockIdx.x * 256 + threadIdx.x;
    if (e < NE) atomicAdd(&fill[dst[e]], 1);
}

// ---------------------------------------------------------------- CSR build: exclusive scan (1 block)
__global__ __launch_bounds__(1024) void scan_kernel(const int* __restrict__ cnt,
                                                    int* __restrict__ rp) {
    __shared__ int wsum[16];
    __shared__ int carry_s;
    int t = threadIdx.x;
    int lane = t & 63, w = t >> 6;
    if (t == 0) { carry_s = 0; rp[0] = 0; }
    __syncthreads();
    for (int base = 0; base < NN; base += 1024) {
        int i = base + t;
        int v = (i < NN) ? cnt[i] : 0;
        int sv = v;
        #pragma unroll
        for (int off = 1; off < 64; off <<= 1) {
            int u = __shfl_up(sv, off);
            if (lane >= off) sv += u;
        }
        if (lane == 63) wsum[w] = sv;
        __syncthreads();
        int woff = carry_s;
        for (int j = 0; j < w; ++j) woff += wsum[j];
        if (i < NN) rp[i + 1] = sv + woff;
        __syncthreads();
        if (t == 0) {
            int tot = 0;
            for (int j = 0; j < 16; ++j) tot += wsum[j];
            carry_s += tot;
        }
        __syncthreads();
    }
}

// ---------------------------------------------------------------- CSR build: place edges
__global__ void place_kernel(const int* __restrict__ src, const int* __restrict__ dst,
                             const int* __restrict__ et, const float* __restrict__ rm,
                             const int* __restrict__ rp, int* __restrict__ fill,
                             int* __restrict__ csr_s, float* __restrict__ csr_w) {
    int e = blockIdx.x * 256 + threadIdx.x;
    if (e < NE) {
        int d = dst[e];
        int pos = rp[d] + atomicAdd(&fill[d], 1);
        csr_s[pos] = src[e];
        csr_w[pos] = rm[et[e] - 1];
    }
}

// ---------------------------------------------------------------- embedding gather
__global__ void embed_kernel(const int* __restrict__ ids, const float* __restrict__ tab,
                             float* __restrict__ x) {
    int tid = blockIdx.x * 256 + threadIdx.x;   // NN*32 threads
    int n = tid >> 5, c = tid & 31;
    if (n < NN) {
        const float4* srcp = (const float4*)(tab + (size_t)(ids[n] + 1) * DD);
        ((float4*)(x + (size_t)n * DD))[c] = srcp[c];
    }
}

// ---------------------------------------------------------------- pre-transpose GRU weights
// WT[mat][k][d] = W[mat<3?ih:hh][(g*128+d)][k], mat in 0..5
__global__ void transpose_w_kernel(const float* __restrict__ Wih, const float* __restrict__ Whh,
                                   float* __restrict__ WT) {
    int idx = blockIdx.x * 256 + threadIdx.x;   // 6*128*128 = 98304
    int mat = idx >> 14;
    int k = (idx >> 7) & 127;
    int d = idx & 127;
    const float* W = (mat < 3) ? (Wih + (size_t)mat * 16384) : (Whh + (size_t)(mat - 3) * 16384);
    WT[idx] = W[d * 128 + k];
}

// ---------------------------------------------------------------- m = x @ W  (W is [k][d] row-major)
__global__ __launch_bounds__(512, 6) void gemm_m_kernel(const float* __restrict__ x,
                                                        const float* __restrict__ W,
                                                        float* __restrict__ out) {
    __shared__ float sX[64 * DD];   // 32 KB
    __shared__ float sW[32 * DD];   // 16 KB (k-chunk)
    int t = threadIdx.x;
    int b0 = blockIdx.x * 64;
    #pragma unroll
    for (int it = 0; it < 4; ++it) {
        int idx = it * 512 + t;          // 2048 float4 slots
        int n = idx >> 5, c = idx & 31;
        int row = b0 + n;
        float4 v = make_float4(0.f, 0.f, 0.f, 0.f);
        if (row < NN) v = ((const float4*)(x + (size_t)row * DD))[c];
        ((float4*)sX)[idx] = v;
    }
    int ng = t >> 5, dg = t & 31;
    float acc[4][4];
    #pragma unroll
    for (int i = 0; i < 4; ++i)
        #pragma unroll
        for (int j = 0; j < 4; ++j) acc[i][j] = 0.f;
    for (int kc = 0; kc < 4; ++kc) {
        __syncthreads();
        const float4* wsrc = (const float4*)(W + kc * 32 * DD);
        ((float4*)sW)[t] = wsrc[t];
        ((float4*)sW)[t + 512] = wsrc[t + 512];
        __syncthreads();
        #pragma unroll 4
        for (int k0 = 0; k0 < 32; ++k0) {
            float4 w4 = ((const float4*)(sW + k0 * DD))[dg];
            int k = kc * 32 + k0;
            #pragma unroll
            for (int i = 0; i < 4; ++i) {
                float a = sX[(ng + 16 * i) * DD + k];
                acc[i][0] += a * w4.x; acc[i][1] += a * w4.y;
                acc[i][2] += a * w4.z; acc[i][3] += a * w4.w;
            }
        }
    }
    #pragma unroll
    for (int i = 0; i < 4; ++i) {
        int row = b0 + ng + 16 * i;
        if (row < NN) {
            float4 v = make_float4(acc[i][0], acc[i][1], acc[i][2], acc[i][3]);
            ((float4*)(out + (size_t)row * DD))[dg] = v;
        }
    }
}

// ---------------------------------------------------------------- CSR aggregation (no atomics)
__global__ __launch_bounds__(256) void agg_kernel(const float* __restrict__ m,
                                                  const int* __restrict__ rp,
                                                  const int* __restrict__ csr_s,
                                                  const float* __restrict__ csr_w,
                                                  float* __restrict__ agg) {
    int t = threadIdx.x;
    int grp = t >> 5, c = t & 31;
    int n = blockIdx.x * 8 + grp;
    if (n >= NN) return;
    int e0 = rp[n], e1 = rp[n + 1];
    float4 acc = make_float4(0.f, 0.f, 0.f, 0.f);
    int e = e0;
    for (; e + 1 < e1; e += 2) {
        float w0 = csr_w[e], w1 = csr_w[e + 1];
        int s0 = csr_s[e], s1 = csr_s[e + 1];
        float4 v0 = ((const float4*)(m + (size_t)s0 * DD))[c];
        float4 v1 = ((const float4*)(m + (size_t)s1 * DD))[c];
        acc.x += w0 * v0.x; acc.y += w0 * v0.y; acc.z += w0 * v0.z; acc.w += w0 * v0.w;
        acc.x += w1 * v1.x; acc.y += w1 * v1.y; acc.z += w1 * v1.z; acc.w += w1 * v1.w;
    }
    if (e < e1) {
        float w0 = csr_w[e];
        int s0 = csr_s[e];
        float4 v0 = ((const float4*)(m + (size_t)s0 * DD))[c];
        acc.x += w0 * v0.x; acc.y += w0 * v0.y; acc.z += w0 * v0.z; acc.w += w0 * v0.w;
    }
    ((float4*)(agg + (size_t)n * DD))[c] = acc;
}

// ---------------------------------------------------------------- fused GRU (k-chunked weights)
__global__ __launch_bounds__(512, 4) void gru_kernel(const float* __restrict__ agg,
                                                     const float* __restrict__ x,
                                                     const float* __restrict__ WT,
                                                     const float* __restrict__ bih,
                                                     const float* __restrict__ bhh,
                                                     float* __restrict__ xout) {
    __shared__ float sA[64 * DD];   // 32 KB
    __shared__ float sX[64 * DD];   // 32 KB
    __shared__ float sW[32 * DD];   // 16 KB
    int t = threadIdx.x;
    int b0 = blockIdx.x * 64;
    #pragma unroll
    for (int it = 0; it < 4; ++it) {
        int idx = it * 512 + t;
        int n = idx >> 5, c = idx & 31;
        int row = b0 + n;
        float4 va = make_float4(0.f, 0.f, 0.f, 0.f);
        float4 vx = va;
        if (row < NN) {
            va = ((const float4*)(agg + (size_t)row * DD))[c];
            vx = ((const float4*)(x + (size_t)row * DD))[c];
        }
        ((float4*)sA)[idx] = va;
        ((float4*)sX)[idx] = vx;
    }
    int ng = t >> 5, dg = t & 31;
    float rv[4][4], zv[4][4], xn[4][4];
    for (int g = 0; g < 3; ++g) {
        float gi[4][4], gh[4][4];
        #pragma unroll
        for (int i = 0; i < 4; ++i)
            #pragma unroll
            for (int j = 0; j < 4; ++j) { gi[i][j] = 0.f; gh[i][j] = 0.f; }
        // gi = agg @ WT_ih[g]
        for (int kc = 0; kc < 4; ++kc) {
            __syncthreads();
            const float4* wsrc = (const float4*)(WT + ((size_t)g * 128 + kc * 32) * DD);
            ((float4*)sW)[t] = wsrc[t];
            ((float4*)sW)[t + 512] = wsrc[t + 512];
            __syncthreads();
            #pragma unroll 4
            for (int k0 = 0; k0 < 32; ++k0) {
                float4 w4 = ((const float4*)(sW + k0 * DD))[dg];
                int k = kc * 32 + k0;
                #pragma unroll
                for (int i = 0; i < 4; ++i) {
                    float a = sA[(ng + 16 * i) * DD + k];
                    gi[i][0] += a * w4.x; gi[i][1] += a * w4.y;
                    gi[i][2] += a * w4.z; gi[i][3] += a * w4.w;
                }
            }
        }
        // gh = x @ WT_hh[g]
        for (int kc = 0; kc < 4; ++kc) {
            __syncthreads();
            const float4* wsrc = (const float4*)(WT + ((size_t)(3 + g) * 128 + kc * 32) * DD);
            ((float4*)sW)[t] = wsrc[t];
            ((float4*)sW)[t + 512] = wsrc[t + 512];
            __syncthreads();
            #pragma unroll 4
            for (int k0 = 0; k0 < 32; ++k0) {
                float4 w4 = ((const float4*)(sW + k0 * DD))[dg];
                int k = kc * 32 + k0;
                #pragma unroll
                for (int i = 0; i < 4; ++i) {
                    float a = sX[(ng + 16 * i) * DD + k];
                    gh[i][0] += a * w4.x; gh[i][1] += a * w4.y;
                    gh[i][2] += a * w4.z; gh[i][3] += a * w4.w;
                }
            }
        }
        float4 bi4 = ((const float4*)(bih + g * DD))[dg];
        float4 bh4 = ((const float4*)(bhh + g * DD))[dg];
        float bi[4] = {bi4.x, bi4.y, bi4.z, bi4.w};
        float bh[4] = {bh4.x, bh4.y, bh4.z, bh4.w};
        #pragma unroll
        for (int i = 0; i < 4; ++i) {
            #pragma unroll
            for (int j = 0; j < 4; ++j) {
                float giv = gi[i][j] + bi[j];
                float ghv = gh[i][j] + bh[j];
                if (g == 0) {
                    rv[i][j] = 1.0f / (1.0f + expf(-(giv + ghv)));
                } else if (g == 1) {
                    zv[i][j] = 1.0f / (1.0f + expf(-(giv + ghv)));
                } else {
                    float nv = tanhf(giv + rv[i][j] * ghv);
                    float xo = sX[(ng + 16 * i) * DD + 4 * dg + j];
                    xn[i][j] = (1.0f - zv[i][j]) * nv + zv[i][j] * xo;
                }
            }
        }
    }
    #pragma unroll
    for (int i = 0; i < 4; ++i) {
        int row = b0 + ng + 16 * i;
        if (row < NN) {
            float4 v = make_float4(xn[i][0], xn[i][1], xn[i][2], xn[i][3]);
            ((float4*)(xout + (size_t)row * DD))[dg] = v;
        }
    }
}

// ---------------------------------------------------------------- pooling
__global__ void pool1_kernel(const float* __restrict__ x, const float* __restrict__ gw,
                             const float* __restrict__ gb, float* __restrict__ p) {
    int w = threadIdx.x >> 6, lane = threadIdx.x & 63;
    int n = blockIdx.x * 4 + w;                 // NN = 4 * 25000 exactly
    float v = x[(size_t)n * DD + lane] * gw[lane] +
              x[(size_t)n * DD + 64 + lane] * gw[64 + lane];
    #pragma unroll
    for (int o = 32; o > 0; o >>= 1) v += __shfl_xor(v, o);
    if (lane == 0) {
        float s = 1.0f / (1.0f + expf(-(v + gb[0])));
        p[n] = expf(s);                          // s in (0,1): no max-subtract needed
    }
}

__global__ void pool2_kernel(const float* __restrict__ x, const float* __restrict__ p,
                             float* __restrict__ accum, float* __restrict__ den) {
    int t = threadIdx.x;
    int d = t & 127, g = t >> 7;
    int base = blockIdx.x * 256 + g * 128;
    float acc = 0.f, ps = 0.f;
    for (int j = 0; j < 128; ++j) {
        int n = base + j;
        if (n < NN) {
            float pv = p[n];
            acc += pv * x[(size_t)n * DD + d];
            ps += pv;
        }
    }
    __shared__ float red[256];
    __shared__ float rps[2];
    red[t] = acc;
    if (d == 0) rps[g] = ps;
    __syncthreads();
    if (g == 0) {
        atomicAdd(&accum[d], acc + red[128 + d]);
        if (t == 0) atomicAdd(den, rps[0] + rps[1]);
    }
}

__global__ void finalize_kernel(const float* __restrict__ accum, const float* __restrict__ den,
                                float* __restrict__ out) {
    out[threadIdx.x] = accum[threadIdx.x] / den[0];
}

// ---------------------------------------------------------------- launch
extern "C" void kernel_launch(void* const* d_in, const int* in_sizes, int n_in,
                              void* d_out, int out_size, void* d_ws, size_t ws_size,
                              hipStream_t stream) {
    const int*   node_ids    = (const int*)d_in[0];
    const int*   edges       = (const int*)d_in[1];
    const int*   edge_types  = (const int*)d_in[2];
    const float* embed_table = (const float*)d_in[3];
    const float* edge_tab    = (const float*)d_in[4];
    const float* ggnn_w      = (const float*)d_in[5];
    const float* Wih         = (const float*)d_in[6];
    const float* Whh         = (const float*)d_in[7];
    const float* bih         = (const float*)d_in[8];
    const float* bhh         = (const float*)d_in[9];
    const float* gate_w      = (const float*)d_in[10];
    const float* gate_b      = (const float*)d_in[11];
    float* out = (float*)d_out;

    float* ws    = (float*)d_ws;
    float* x     = ws;                                   // N*D
    float* m     = x + (size_t)NN * DD;                  // N*D (doubles as x_next)
    float* agg   = m + (size_t)NN * DD;                  // N*D
    float* WT    = agg + (size_t)NN * DD;                // 6*128*128
    float* csr_w = WT + 6 * 128 * 128;                   // E
    float* p     = csr_w + NE;                           // N
    float* accum = p + NN;                               // 128
    float* den   = accum + DD;                           // 1
    float* rm    = den + 1;                              // 7
    int*   rp    = (int*)(rm + 8);                       // N+1
    int*   fill  = rp + NN + 1;                          // N
    int*   csr_s = fill + NN;                            // E

    const int* src = edges;
    const int* dst = edges + NE;

    // --- one-time prep: edge weights, CSR, embeddings, transposed GRU weights
    rowmean_kernel<<<7, 128, 0, stream>>>(edge_tab, rm);
    hipMemsetAsync(fill, 0, NN * sizeof(int), stream);
    hist_kernel<<<(NE + 255) / 256, 256, 0, stream>>>(dst, fill);
    scan_kernel<<<1, 1024, 0, stream>>>(fill, rp);
    hipMemsetAsync(fill, 0, NN * sizeof(int), stream);
    place_kernel<<<(NE + 255) / 256, 256, 0, stream>>>(src, dst, edge_types, rm, rp, fill,
                                                       csr_s, csr_w);
    embed_kernel<<<NN * 32 / 256, 256, 0, stream>>>(node_ids, embed_table, x);
    transpose_w_kernel<<<6 * 128 * 128 / 256, 256, 0, stream>>>(Wih, Whh, WT);

    // --- 4 GGNN layers
    for (int layer = 0; layer < 4; ++layer) {
        gemm_m_kernel<<<(NN + 63) / 64, 512, 0, stream>>>(x, ggnn_w + (size_t)layer * DD * DD, m);
        agg_kernel<<<(NN + 7) / 8, 256, 0, stream>>>(m, rp, csr_s, csr_w, agg);
        gru_kernel<<<(NN + 63) / 64, 512, 0, stream>>>(agg, x, WT, bih, bhh, m);
        float* tmp = x; x = m; m = tmp;
    }

    // --- global attention pooling
    hipMemsetAsync(accum, 0, (DD + 1) * sizeof(float), stream);
    pool1_kernel<<<NN / 4, 256, 0, stream>>>(x, gate_w, gate_b, p);
    pool2_kernel<<<(NN + 255) / 256, 256, 0, stream>>>(x, p, accum, den);
    finalize_kernel<<<1, 128, 0, stream>>>(accum, den, out);
}

// Round 3
// 1296.039 us; speedup vs baseline: 5.8483x; 1.6046x over previous
//
#include <hip/hip_runtime.h>
#include <math.h>

#define NN 100000
#define NE 800000
#define DD 128

typedef __attribute__((ext_vector_type(8))) short short8;
typedef __attribute__((ext_vector_type(4))) float floatx4;
typedef unsigned int uint_t;

__device__ __forceinline__ unsigned short f2bf(float f) {
    unsigned u = __float_as_uint(f);
    return (unsigned short)((u + 0x7fffu + ((u >> 16) & 1u)) >> 16);
}
__device__ __forceinline__ uint_t pack_split(float f) {
    unsigned short h = f2bf(f);
    float hf = __uint_as_float((unsigned)h << 16);
    unsigned short l = f2bf(f - hf);
    return ((uint_t)h << 16) | (uint_t)l;
}
__device__ __forceinline__ float unpack_sum(uint_t p) {
    return __uint_as_float(p & 0xffff0000u) + __uint_as_float(p << 16);
}

// ---------------------------------------------------------------- row means of edge-type table
__global__ void rowmean_kernel(const float* __restrict__ tab, float* __restrict__ rm) {
    int r = blockIdx.x;
    int t = threadIdx.x;
    float v = tab[r * DD + t];
    #pragma unroll
    for (int o = 32; o > 0; o >>= 1) v += __shfl_xor(v, o);
    __shared__ float red[2];
    if ((t & 63) == 0) red[t >> 6] = v;
    __syncthreads();
    if (t == 0) rm[r] = (red[0] + red[1]) * (1.0f / DD);
}

// ---------------------------------------------------------------- CSR build
__global__ void hist_kernel(const int* __restrict__ dst, int* __restrict__ fill) {
    int e = blockIdx.x * 256 + threadIdx.x;
    if (e < NE) atomicAdd(&fill[dst[e]], 1);
}

__global__ __launch_bounds__(1024) void scan_kernel(const int* __restrict__ cnt,
                                                    int* __restrict__ rp) {
    __shared__ int wsum[16];
    __shared__ int carry_s;
    int t = threadIdx.x;
    int lane = t & 63, w = t >> 6;
    if (t == 0) { carry_s = 0; rp[0] = 0; }
    __syncthreads();
    for (int base = 0; base < NN; base += 1024) {
        int i = base + t;
        int v = (i < NN) ? cnt[i] : 0;
        int sv = v;
        #pragma unroll
        for (int off = 1; off < 64; off <<= 1) {
            int u = __shfl_up(sv, off);
            if (lane >= off) sv += u;
        }
        if (lane == 63) wsum[w] = sv;
        __syncthreads();
        int woff = carry_s;
        for (int j = 0; j < w; ++j) woff += wsum[j];
        if (i < NN) rp[i + 1] = sv + woff;
        __syncthreads();
        if (t == 0) {
            int tot = 0;
            for (int j = 0; j < 16; ++j) tot += wsum[j];
            carry_s += tot;
        }
        __syncthreads();
    }
}

__global__ void place_kernel(const int* __restrict__ src, const int* __restrict__ dst,
                             const int* __restrict__ et, const float* __restrict__ rm,
                             const int* __restrict__ rp, int* __restrict__ fill,
                             int* __restrict__ csr_s, float* __restrict__ csr_w) {
    int e = blockIdx.x * 256 + threadIdx.x;
    if (e < NE) {
        int d = dst[e];
        int pos = rp[d] + atomicAdd(&fill[d], 1);
        csr_s[pos] = src[e];
        csr_w[pos] = rm[et[e] - 1];
    }
}

// ---------------------------------------------------------------- embedding gather → packed hi/lo
__global__ void embed_kernel(const int* __restrict__ ids, const float* __restrict__ tab,
                             uint_t* __restrict__ xp) {
    int tid = blockIdx.x * 256 + threadIdx.x;   // NN*32
    int n = tid >> 5, c = tid & 31;
    if (n < NN) {
        float4 v = ((const float4*)(tab + (size_t)(ids[n] + 1) * DD))[c];
        uint4 o;
        o.x = pack_split(v.x); o.y = pack_split(v.y);
        o.z = pack_split(v.z); o.w = pack_split(v.w);
        ((uint4*)(xp + (size_t)n * DD))[c] = o;
    }
}

// ---------------------------------------------------------------- weight prep: split + swizzle to MFMA frag order
// mats 0..2: Whh gates r,z,n | 3..5: Wih gates r,z,n | 6..9: ggnn layer W
// layout per (mat,chunk,split): 4096 bf16, addr = ((col>>4)*4 + (klo>>3))*128 + (col&15)*8 + (klo&7)
__global__ void wprep_kernel(const float* __restrict__ Wih, const float* __restrict__ Whh,
                             const float* __restrict__ G, unsigned short* __restrict__ WB) {
    int idx = blockIdx.x * 256 + threadIdx.x;   // 10*16384
    int mat = idx >> 14;
    int rem = idx & 16383;
    int col = rem & 127, kk = rem >> 7;
    float w;
    if (mat < 3)      w = Whh[((size_t)mat * 128 + col) * 128 + kk];
    else if (mat < 6) w = Wih[((size_t)(mat - 3) * 128 + col) * 128 + kk];
    else              w = G[(size_t)(mat - 6) * 16384 + (size_t)kk * 128 + col];
    int chunk = kk >> 5, klo = kk & 31;
    int inoff = ((col >> 4) * 4 + (klo >> 3)) * 128 + (col & 15) * 8 + (klo & 7);
    unsigned short h = f2bf(w);
    float hf = __uint_as_float((unsigned)h << 16);
    unsigned short l = f2bf(w - hf);
    size_t base = (size_t)((mat * 4 + chunk) * 2) * 4096;
    WB[base + inoff] = h;
    WB[base + 4096 + inoff] = l;
}

// ---------------------------------------------------------------- m = x @ W_l  (split-bf16 MFMA)
__global__ __launch_bounds__(512) void gemm_mfma_kernel(const uint_t* __restrict__ xp,
                                                        const unsigned short* __restrict__ WB,
                                                        int mat, uint_t* __restrict__ mp) {
    __shared__ unsigned short sA[2][4096];   // 16 KB: 128 rows x 32 k, hi/lo
    __shared__ unsigned short sB[8192];      // 16 KB: hi/lo images
    int t = threadIdx.x;
    int brow = blockIdx.x * 128;
    int l = t & 63, w = t >> 6;
    int rowgrp = w >> 2, colgrp = w & 3;
    int lg = l >> 4, lc = l & 15;
    floatx4 acc[4][2];
    #pragma unroll
    for (int i = 0; i < 4; ++i)
        #pragma unroll
        for (int j = 0; j < 2; ++j) acc[i][j] = (floatx4)0.f;

    for (int kc = 0; kc < 4; ++kc) {
        __syncthreads();
        // stage A
        #pragma unroll
        for (int h = 0; h < 2; ++h) {
            int id = t + h * 512;
            int row = id >> 3, q = id & 7;
            int grow = brow + row;
            uint4 p = make_uint4(0, 0, 0, 0);
            if (grow < NN) p = ((const uint4*)(xp + (size_t)grow * DD + kc * 32))[q];
            unsigned uh0 = (p.x >> 16) | (p.y & 0xffff0000u);
            unsigned uh1 = (p.z >> 16) | (p.w & 0xffff0000u);
            unsigned ul0 = (p.x & 0xffffu) | (p.y << 16);
            unsigned ul1 = (p.z & 0xffffu) | (p.w << 16);
            int soff = (((row >> 4) * 4 + (q >> 1)) * 16 + (row & 15)) * 8 + (q & 1) * 4;
            *(unsigned*)&sA[0][soff] = uh0; *(unsigned*)&sA[0][soff + 2] = uh1;
            *(unsigned*)&sA[1][soff] = ul0; *(unsigned*)&sA[1][soff + 2] = ul1;
        }
        // stage B: 2 images (hi,lo) = 1024 uint4
        #pragma unroll
        for (int h = 0; h < 2; ++h) {
            int id = t + h * 512;
            ((uint4*)sB)[id] = ((const uint4*)WB)[(size_t)((mat * 4 + kc) * 2) * 512 + id];
        }
        __syncthreads();
        short8 aH[4], aL[4];
        #pragma unroll
        for (int i = 0; i < 4; ++i) {
            int off = (((rowgrp * 4 + i) * 4 + lg) * 16 + lc) * 8;
            aH[i] = *(const short8*)&sA[0][off];
            aL[i] = *(const short8*)&sA[1][off];
        }
        #pragma unroll
        for (int j = 0; j < 2; ++j) {
            int boff = (((colgrp * 2 + j) * 4 + lg) * 16 + lc) * 8;
            short8 bH = *(const short8*)&sB[boff];
            short8 bL = *(const short8*)&sB[4096 + boff];
            #pragma unroll
            for (int i = 0; i < 4; ++i) {
                acc[i][j] = __builtin_amdgcn_mfma_f32_16x16x32_bf16(aH[i], bH, acc[i][j], 0, 0, 0);
                acc[i][j] = __builtin_amdgcn_mfma_f32_16x16x32_bf16(aH[i], bL, acc[i][j], 0, 0, 0);
                acc[i][j] = __builtin_amdgcn_mfma_f32_16x16x32_bf16(aL[i], bH, acc[i][j], 0, 0, 0);
            }
        }
    }
    #pragma unroll
    for (int i = 0; i < 4; ++i)
        #pragma unroll
        for (int j = 0; j < 2; ++j) {
            int col = (colgrp * 2 + j) * 16 + lc;
            #pragma unroll
            for (int r = 0; r < 4; ++r) {
                int row = brow + (rowgrp * 4 + i) * 16 + lg * 4 + r;
                if (row < NN) mp[(size_t)row * DD + col] = pack_split(acc[i][j][r]);
            }
        }
}

// ---------------------------------------------------------------- CSR aggregation (packed in/out)
__global__ __launch_bounds__(256) void agg_kernel(const uint_t* __restrict__ m,
                                                  const int* __restrict__ rp,
                                                  const int* __restrict__ csr_s,
                                                  const float* __restrict__ csr_w,
                                                  uint_t* __restrict__ aggp) {
    int t = threadIdx.x;
    int grp = t >> 5, c = t & 31;
    int n = blockIdx.x * 8 + grp;
    if (n >= NN) return;
    int e0 = rp[n], e1 = rp[n + 1];
    float4 acc = make_float4(0.f, 0.f, 0.f, 0.f);
    for (int e = e0; e < e1; ++e) {
        float w0 = csr_w[e];
        int s0 = csr_s[e];
        uint4 p = ((const uint4*)(m + (size_t)s0 * DD))[c];
        acc.x += w0 * unpack_sum(p.x);
        acc.y += w0 * unpack_sum(p.y);
        acc.z += w0 * unpack_sum(p.z);
        acc.w += w0 * unpack_sum(p.w);
    }
    uint4 o;
    o.x = pack_split(acc.x); o.y = pack_split(acc.y);
    o.z = pack_split(acc.z); o.w = pack_split(acc.w);
    ((uint4*)(aggp + (size_t)n * DD))[c] = o;
}

// ---------------------------------------------------------------- fused GRU (split-bf16 MFMA)
// pass 0: A = x   (mats 0..2: Whh r,z,n) → accR, accZ, accN
// pass 1: A = agg (mats 3..5: Wih r,z,n) → accR, accZ, accI
__global__ __launch_bounds__(512) void gru_mfma_kernel(const uint_t* __restrict__ aggp,
                                                       const uint_t* __restrict__ xp,
                                                       const unsigned short* __restrict__ WB,
                                                       const float* __restrict__ bih,
                                                       const float* __restrict__ bhh,
                                                       uint_t* __restrict__ xo) {
    __shared__ unsigned short sA[2][4096];   // 16 KB
    __shared__ unsigned short sB[24576];     // 48 KB: 3 mats x hi/lo
    int t = threadIdx.x;
    int brow = blockIdx.x * 128;
    int l = t & 63, w = t >> 6;
    int rowgrp = w >> 2, colgrp = w & 3;
    int lg = l >> 4, lc = l & 15;
    floatx4 accR[4][2], accZ[4][2], accN[4][2], accI[4][2];
    #pragma unroll
    for (int i = 0; i < 4; ++i)
        #pragma unroll
        for (int j = 0; j < 2; ++j) {
            accR[i][j] = (floatx4)0.f; accZ[i][j] = (floatx4)0.f;
            accN[i][j] = (floatx4)0.f; accI[i][j] = (floatx4)0.f;
        }

    for (int pass = 0; pass < 2; ++pass) {
        const uint_t* Ap = pass ? aggp : xp;
        int matbase = pass ? 3 : 0;
        for (int kc = 0; kc < 4; ++kc) {
            __syncthreads();
            // stage A
            #pragma unroll
            for (int h = 0; h < 2; ++h) {
                int id = t + h * 512;
                int row = id >> 3, q = id & 7;
                int grow = brow + row;
                uint4 p = make_uint4(0, 0, 0, 0);
                if (grow < NN) p = ((const uint4*)(Ap + (size_t)grow * DD + kc * 32))[q];
                unsigned uh0 = (p.x >> 16) | (p.y & 0xffff0000u);
                unsigned uh1 = (p.z >> 16) | (p.w & 0xffff0000u);
                unsigned ul0 = (p.x & 0xffffu) | (p.y << 16);
                unsigned ul1 = (p.z & 0xffffu) | (p.w << 16);
                int soff = (((row >> 4) * 4 + (q >> 1)) * 16 + (row & 15)) * 8 + (q & 1) * 4;
                *(unsigned*)&sA[0][soff] = uh0; *(unsigned*)&sA[0][soff + 2] = uh1;
                *(unsigned*)&sA[1][soff] = ul0; *(unsigned*)&sA[1][soff + 2] = ul1;
            }
            // stage B: 6 images = 3072 uint4
            #pragma unroll
            for (int h = 0; h < 6; ++h) {
                int id = t + h * 512;
                int img = id >> 9, part = id & 511;
                int gmat = matbase + (img >> 1), s = img & 1;
                ((uint4*)sB)[id] = ((const uint4*)WB)[(size_t)(((gmat * 4 + kc) * 2) + s) * 512 + part];
            }
            __syncthreads();
            short8 aH[4], aL[4];
            #pragma unroll
            for (int i = 0; i < 4; ++i) {
                int off = (((rowgrp * 4 + i) * 4 + lg) * 16 + lc) * 8;
                aH[i] = *(const short8*)&sA[0][off];
                aL[i] = *(const short8*)&sA[1][off];
            }
            #pragma unroll
            for (int m = 0; m < 3; ++m) {
                floatx4 (*accp)[2] = (m == 0) ? accR : (m == 1) ? accZ : (pass ? accI : accN);
                #pragma unroll
                for (int j = 0; j < 2; ++j) {
                    int boff = (((colgrp * 2 + j) * 4 + lg) * 16 + lc) * 8;
                    short8 bH = *(const short8*)&sB[(m * 2) * 4096 + boff];
                    short8 bL = *(const short8*)&sB[(m * 2 + 1) * 4096 + boff];
                    #pragma unroll
                    for (int i = 0; i < 4; ++i) {
                        accp[i][j] = __builtin_amdgcn_mfma_f32_16x16x32_bf16(aH[i], bH, accp[i][j], 0, 0, 0);
                        accp[i][j] = __builtin_amdgcn_mfma_f32_16x16x32_bf16(aH[i], bL, accp[i][j], 0, 0, 0);
                        accp[i][j] = __builtin_amdgcn_mfma_f32_16x16x32_bf16(aL[i], bH, accp[i][j], 0, 0, 0);
                    }
                }
            }
        }
    }
    // epilogue: gates + blend
    #pragma unroll
    for (int i = 0; i < 4; ++i)
        #pragma unroll
        for (int j = 0; j < 2; ++j) {
            int col = (colgrp * 2 + j) * 16 + lc;
            float bIr = bih[col],       bHr = bhh[col];
            float bIz = bih[128 + col], bHz = bhh[128 + col];
            float bIn = bih[256 + col], bHn = bhh[256 + col];
            #pragma unroll
            for (int r = 0; r < 4; ++r) {
                int row = brow + (rowgrp * 4 + i) * 16 + lg * 4 + r;
                if (row < NN) {
                    float rr = 1.0f / (1.0f + expf(-(accR[i][j][r] + bIr + bHr)));
                    float tt = rr * (accN[i][j][r] + bHn);
                    float zz = 1.0f / (1.0f + expf(-(accZ[i][j][r] + bIz + bHz)));
                    float nn = tanhf(accI[i][j][r] + bIn + tt);
                    float h = unpack_sum(xp[(size_t)row * DD + col]);
                    xo[(size_t)row * DD + col] = pack_split((1.0f - zz) * nn + zz * h);
                }
            }
        }
}

// ---------------------------------------------------------------- pooling (packed x)
__global__ void pool1_kernel(const uint_t* __restrict__ xp, const float* __restrict__ gw,
                             const float* __restrict__ gb, float* __restrict__ p) {
    int w = threadIdx.x >> 6, lane = threadIdx.x & 63;
    int n = blockIdx.x * 4 + w;
    float v = unpack_sum(xp[(size_t)n * DD + lane]) * gw[lane] +
              unpack_sum(xp[(size_t)n * DD + 64 + lane]) * gw[64 + lane];
    #pragma unroll
    for (int o = 32; o > 0; o >>= 1) v += __shfl_xor(v, o);
    if (lane == 0) {
        float s = 1.0f / (1.0f + expf(-(v + gb[0])));
        p[n] = expf(s);
    }
}

__global__ void pool2_kernel(const uint_t* __restrict__ xp, const float* __restrict__ p,
                             float* __restrict__ accum, float* __restrict__ den) {
    int t = threadIdx.x;
    int d = t & 127, g = t >> 7;
    int base = blockIdx.x * 256 + g * 128;
    float acc = 0.f, ps = 0.f;
    for (int j = 0; j < 128; ++j) {
        int n = base + j;
        if (n < NN) {
            float pv = p[n];
            acc += pv * unpack_sum(xp[(size_t)n * DD + d]);
            ps += pv;
        }
    }
    __shared__ float red[256];
    __shared__ float rps[2];
    red[t] = acc;
    if (d == 0) rps[g] = ps;
    __syncthreads();
    if (g == 0) {
        atomicAdd(&accum[d], acc + red[128 + d]);
        if (t == 0) atomicAdd(den, rps[0] + rps[1]);
    }
}

__global__ void finalize_kernel(const float* __restrict__ accum, const float* __restrict__ den,
                                float* __restrict__ out) {
    out[threadIdx.x] = accum[threadIdx.x] / den[0];
}

// ---------------------------------------------------------------- launch
extern "C" void kernel_launch(void* const* d_in, const int* in_sizes, int n_in,
                              void* d_out, int out_size, void* d_ws, size_t ws_size,
                              hipStream_t stream) {
    const int*   node_ids    = (const int*)d_in[0];
    const int*   edges       = (const int*)d_in[1];
    const int*   edge_types  = (const int*)d_in[2];
    const float* embed_table = (const float*)d_in[3];
    const float* edge_tab    = (const float*)d_in[4];
    const float* ggnn_w      = (const float*)d_in[5];
    const float* Wih         = (const float*)d_in[6];
    const float* Whh         = (const float*)d_in[7];
    const float* bih         = (const float*)d_in[8];
    const float* bhh         = (const float*)d_in[9];
    const float* gate_w      = (const float*)d_in[10];
    const float* gate_b      = (const float*)d_in[11];
    float* out = (float*)d_out;

    char* wsb = (char*)d_ws;
    uint_t* x_pk   = (uint_t*)wsb;                               // N*D uints
    uint_t* m_pk   = x_pk + (size_t)NN * DD;                     // N*D (also x_next)
    uint_t* agg_pk = m_pk + (size_t)NN * DD;                     // N*D
    unsigned short* WB = (unsigned short*)(agg_pk + (size_t)NN * DD);  // 10*4*2*4096
    float* csr_w = (float*)(WB + 10 * 4 * 2 * 4096);             // E
    float* p     = csr_w + NE;                                   // N
    float* accum = p + NN;                                       // 128
    float* den   = accum + DD;                                   // 1
    float* rm    = den + 1;                                      // 7(+1)
    int*   rp    = (int*)(rm + 8);                               // N+1
    int*   fill  = rp + NN + 1;                                  // N
    int*   csr_s = fill + NN;                                    // E

    const int* src = edges;
    const int* dst = edges + NE;

    // one-time prep
    rowmean_kernel<<<7, 128, 0, stream>>>(edge_tab, rm);
    hipMemsetAsync(fill, 0, NN * sizeof(int), stream);
    hist_kernel<<<(NE + 255) / 256, 256, 0, stream>>>(dst, fill);
    scan_kernel<<<1, 1024, 0, stream>>>(fill, rp);
    hipMemsetAsync(fill, 0, NN * sizeof(int), stream);
    place_kernel<<<(NE + 255) / 256, 256, 0, stream>>>(src, dst, edge_types, rm, rp, fill,
                                                       csr_s, csr_w);
    embed_kernel<<<NN * 32 / 256, 256, 0, stream>>>(node_ids, embed_table, x_pk);
    wprep_kernel<<<640, 256, 0, stream>>>(Wih, Whh, ggnn_w, WB);

    // 4 GGNN layers
    int nblk = (NN + 127) / 128;
    for (int layer = 0; layer < 4; ++layer) {
        gemm_mfma_kernel<<<nblk, 512, 0, stream>>>(x_pk, WB, 6 + layer, m_pk);
        agg_kernel<<<(NN + 7) / 8, 256, 0, stream>>>(m_pk, rp, csr_s, csr_w, agg_pk);
        gru_mfma_kernel<<<nblk, 512, 0, stream>>>(agg_pk, x_pk, WB, bih, bhh, m_pk);
        uint_t* tmp = x_pk; x_pk = m_pk; m_pk = tmp;
    }

    // global attention pooling
    hipMemsetAsync(accum, 0, (DD + 1) * sizeof(float), stream);
    pool1_kernel<<<NN / 4, 256, 0, stream>>>(x_pk, gate_w, gate_b, p);
    pool2_kernel<<<(NN + 255) / 256, 256, 0, stream>>>(x_pk, p, accum, den);
    finalize_kernel<<<1, 128, 0, stream>>>(accum, den, out);
}